// Round 1
// baseline (91.310 us; speedup 1.0000x reference)
//
#include <hip/hip_runtime.h>

#define NSEG 4096
#define DD   128   // feature dim

// ---------------- Kernel 1: gate[n] = dot(feat[n,:], w) + b ----------------
// One 64-lane wave handles 2 rows: lanes 0-31 -> row 2w, lanes 32-63 -> row 2w+1.
// Each lane loads one float4 (4 cols); 32 lanes cover the 128-col row.
__global__ void gate_kernel(const float* __restrict__ feat,
                            const float* __restrict__ gw,
                            const float* __restrict__ gb,
                            float* __restrict__ gate, int N) {
    int wid  = (blockIdx.x * blockDim.x + threadIdx.x) >> 6;
    int lane = threadIdx.x & 63;
    int half = lane >> 5;
    int l32  = lane & 31;
    int row  = wid * 2 + half;

    float4 w4 = ((const float4*)gw)[l32];
    float dot = 0.0f;
    if (row < N) {
        float4 v = ((const float4*)feat)[row * 32 + l32];
        dot = v.x * w4.x + v.y * w4.y + v.z * w4.z + v.w * w4.w;
    }
    // reduce across the 32-lane half (xor masks < 32 stay within the half)
    #pragma unroll
    for (int off = 16; off; off >>= 1) dot += __shfl_xor(dot, off);
    if (l32 == 0 && row < N) gate[row] = dot + gb[0];
}

// ---------------- Kernel 2: segment boundaries from sorted ids ----------------
// seg_start[g] = first index n with seg[n] >= g ; seg_start[NSEG] = N.
__global__ void bounds_kernel(const int* __restrict__ seg,
                              int* __restrict__ seg_start, int N) {
    int i = blockIdx.x * blockDim.x + threadIdx.x;
    int stride = gridDim.x * blockDim.x;
    for (int n = i; n < N; n += stride) {
        int cur  = seg[n];
        int prev = (n == 0) ? -1 : seg[n - 1];
        for (int g = prev + 1; g <= cur; ++g) seg_start[g] = n;
        if (n == N - 1) {
            for (int g = cur + 1; g <= NSEG; ++g) seg_start[g] = N;
        }
    }
}

// ---------------- Kernel 3: per-segment stable softmax, in place ----------------
// One wave per segment. gate[] becomes alpha[] (= exp(g-m)/sum).
__global__ void softmax_kernel(float* __restrict__ gate,
                               const int* __restrict__ seg_start) {
    int wid  = (blockIdx.x * blockDim.x + threadIdx.x) >> 6;
    int lane = threadIdx.x & 63;
    if (wid >= NSEG) return;
    int s = seg_start[wid];
    int e = seg_start[wid + 1];

    float m = -INFINITY;
    for (int i = s + lane; i < e; i += 64) m = fmaxf(m, gate[i]);
    #pragma unroll
    for (int off = 32; off; off >>= 1) m = fmaxf(m, __shfl_xor(m, off));

    float sum = 0.0f;
    for (int i = s + lane; i < e; i += 64) {
        float ev = expf(gate[i] - m);
        gate[i] = ev;           // each index owned by exactly one lane
        sum += ev;
    }
    #pragma unroll
    for (int off = 32; off; off >>= 1) sum += __shfl_xor(sum, off);

    float inv = 1.0f / sum;     // empty segment -> no writes anyway
    for (int i = s + lane; i < e; i += 64) gate[i] *= inv;
}

// ---------------- Kernel 4: readout[g,:] = sum_n alpha[n] * feat[n,:] ----------------
// One block per segment. 8 row-groups x 32 lanes x float4; LDS tree reduce.
__global__ void readout_kernel(const float* __restrict__ feat,
                               const float* __restrict__ alpha,
                               const int* __restrict__ seg_start,
                               float* __restrict__ out) {
    __shared__ float4 red[8][32];
    int g  = blockIdx.x;
    int t  = threadIdx.x;
    int rg = t >> 5;    // row group 0..7
    int c  = t & 31;    // float4 column 0..31
    int s = seg_start[g];
    int e = seg_start[g + 1];

    float4 acc = {0.f, 0.f, 0.f, 0.f};
    for (int n = s + rg; n < e; n += 8) {
        float a  = alpha[n];
        float4 v = ((const float4*)feat)[n * 32 + c];
        acc.x += v.x * a; acc.y += v.y * a; acc.z += v.z * a; acc.w += v.w * a;
    }
    red[rg][c] = acc;
    __syncthreads();
    if (rg == 0) {
        float4 r = red[0][c];
        #pragma unroll
        for (int k = 1; k < 8; ++k) {
            float4 v = red[k][c];
            r.x += v.x; r.y += v.y; r.z += v.z; r.w += v.w;
        }
        ((float4*)out)[g * 32 + c] = r;
    }
}

// ---------------- launch ----------------
extern "C" void kernel_launch(void* const* d_in, const int* in_sizes, int n_in,
                              void* d_out, int out_size, void* d_ws, size_t ws_size,
                              hipStream_t stream) {
    const float* feat = (const float*)d_in[0];
    const float* gw   = (const float*)d_in[1];
    const float* gb   = (const float*)d_in[2];
    const int*   seg  = (const int*)d_in[3];
    int N = in_sizes[0] / DD;                       // 500000

    float* gate      = (float*)d_ws;                                // N floats
    int*   seg_start = (int*)((char*)d_ws + (size_t)N * sizeof(float)); // NSEG+1 ints

    // K1: gate dot products — 2 rows per wave
    int waves   = (N + 1) / 2;
    int blocks1 = (waves * 64 + 255) / 256;
    gate_kernel<<<blocks1, 256, 0, stream>>>(feat, gw, gb, gate, N);

    // K2: segment boundaries
    bounds_kernel<<<1024, 256, 0, stream>>>(seg, seg_start, N);

    // K3: per-segment softmax (gate -> alpha in place), one wave per segment
    softmax_kernel<<<NSEG / 4, 256, 0, stream>>>(gate, seg_start);

    // K4: weighted segment-sum readout, one block per segment
    readout_kernel<<<NSEG, 256, 0, stream>>>(feat, gate, seg_start, (float*)d_out);
}

// Round 2
// 80.647 us; speedup vs baseline: 1.1322x; 1.1322x over previous
//
#include <hip/hip_runtime.h>
#include <math.h>

#define NSEG 4096
#define DD   128
#define CAP  2048   // LDS gate capacity in rows; binomial(500k,1/4096) max ~170 << 2048

// ---------------- Kernel 1: segment boundaries from sorted ids ----------------
// seg_start[g] = first index n with seg[n] >= g ; seg_start[NSEG] = N.
__global__ void bounds_kernel(const int* __restrict__ seg,
                              int* __restrict__ seg_start, int N) {
    int i = blockIdx.x * blockDim.x + threadIdx.x;
    int stride = gridDim.x * blockDim.x;
    for (int n = i; n < N; n += stride) {
        int cur  = seg[n];
        int prev = (n == 0) ? -1 : seg[n - 1];
        for (int g = prev + 1; g <= cur; ++g) seg_start[g] = n;
        if (n == N - 1) {
            for (int g = cur + 1; g <= NSEG; ++g) seg_start[g] = N;
        }
    }
}

// ---------------- Kernel 2: fused gate + softmax + weighted readout ----------------
// One 256-thread block per segment (contiguous row range [s,e)).
// Pass 1 reads the slice from HBM computing gate -> LDS; pass 2 re-reads the
// same slice (L2-hot) for the alpha-weighted sum. Single HBM pass over feat.
__global__ __launch_bounds__(256) void fused_kernel(
        const float* __restrict__ feat,
        const float* __restrict__ gw,
        const float* __restrict__ gb,
        const int*  __restrict__ seg_start,
        float* __restrict__ spill,      // N-float fallback for absurd segments
        float* __restrict__ out) {
    __shared__ float  gate_s[CAP];
    __shared__ float4 red[8][32];
    __shared__ float  wred[8];

    int g   = blockIdx.x;
    int s   = seg_start[g];
    int e   = seg_start[g + 1];
    int len = e - s;
    float* gbuf = (len <= CAP) ? gate_s : (spill + s);

    int tid  = threadIdx.x;
    int wave = tid >> 6;
    int lane = tid & 63;
    int half = lane >> 5;
    int l32  = lane & 31;

    float4 w4 = ((const float4*)gw)[l32];
    float  b0 = gb[0];

    // ---- pass 1: gate dot products; block processes 8 rows per iteration ----
    float lmax = -INFINITY;
    for (int row = s + wave * 2 + half; row < e; row += 8) {
        float4 v  = ((const float4*)feat)[row * 32 + l32];
        float dot = v.x * w4.x + v.y * w4.y + v.z * w4.z + v.w * w4.w;
        #pragma unroll
        for (int off = 16; off; off >>= 1) dot += __shfl_xor(dot, off);
        if (l32 == 0) {
            float gv = dot + b0;
            gbuf[row - s] = gv;
            lmax = fmaxf(lmax, gv);
        }
    }
    #pragma unroll
    for (int off = 32; off; off >>= 1) lmax = fmaxf(lmax, __shfl_xor(lmax, off));
    if (lane == 0) wred[wave] = lmax;
    __syncthreads();   // also makes pass-1 gbuf writes visible
    float m = fmaxf(fmaxf(wred[0], wred[1]), fmaxf(wred[2], wred[3]));

    // ---- softmax: exp + sum (gbuf becomes e_i) ----
    float lsum = 0.0f;
    for (int i = tid; i < len; i += 256) {
        float ev = expf(gbuf[i] - m);
        gbuf[i] = ev;
        lsum += ev;
    }
    #pragma unroll
    for (int off = 32; off; off >>= 1) lsum += __shfl_xor(lsum, off);
    if (lane == 0) wred[4 + wave] = lsum;
    __syncthreads();   // makes exp writes + wred[4..7] visible
    float inv = 1.0f / (wred[4] + wred[5] + wred[6] + wred[7]);  // len==0 -> never used

    // ---- pass 2: alpha-weighted sum over the (L2-hot) slice ----
    int rg = tid >> 5;   // row group 0..7
    int c  = tid & 31;   // float4 column
    float4 acc = {0.f, 0.f, 0.f, 0.f};
    for (int n = s + rg; n < e; n += 8) {
        float a  = gbuf[n - s] * inv;
        float4 v = ((const float4*)feat)[n * 32 + c];
        acc.x += v.x * a; acc.y += v.y * a; acc.z += v.z * a; acc.w += v.w * a;
    }
    red[rg][c] = acc;
    __syncthreads();
    if (rg == 0) {
        float4 r = red[0][c];
        #pragma unroll
        for (int k = 1; k < 8; ++k) {
            float4 v = red[k][c];
            r.x += v.x; r.y += v.y; r.z += v.z; r.w += v.w;
        }
        ((float4*)out)[g * 32 + c] = r;   // empty segment -> zeros (acc stays 0)
    }
}

// ---------------- launch ----------------
extern "C" void kernel_launch(void* const* d_in, const int* in_sizes, int n_in,
                              void* d_out, int out_size, void* d_ws, size_t ws_size,
                              hipStream_t stream) {
    const float* feat = (const float*)d_in[0];
    const float* gw   = (const float*)d_in[1];
    const float* gb   = (const float*)d_in[2];
    const int*   seg  = (const int*)d_in[3];
    int N = in_sizes[0] / DD;                        // 500000

    float* spill     = (float*)d_ws;                                    // N floats
    int*   seg_start = (int*)((char*)d_ws + (size_t)N * sizeof(float)); // NSEG+1 ints

    bounds_kernel<<<1024, 256, 0, stream>>>(seg, seg_start, N);
    fused_kernel<<<NSEG, 256, 0, stream>>>(feat, gw, gb, seg_start, spill, (float*)d_out);
}

// Round 3
// 53.245 us; speedup vs baseline: 1.7149x; 1.5147x over previous
//
#include <hip/hip_runtime.h>
#include <math.h>

#define NSEG 4096
#define DD   128

// ---------------- Kernel 1: segment boundaries from sorted ids ----------------
// seg_start[g] = first index n with seg[n] >= g ; seg_start[NSEG] = N.
__global__ void bounds_kernel(const int* __restrict__ seg,
                              int* __restrict__ seg_start, int N) {
    int i = blockIdx.x * blockDim.x + threadIdx.x;
    int stride = gridDim.x * blockDim.x;
    for (int n = i; n < N; n += stride) {
        int cur  = seg[n];
        int prev = (n == 0) ? -1 : seg[n - 1];
        for (int g = prev + 1; g <= cur; ++g) seg_start[g] = n;
        if (n == N - 1) {
            for (int g = cur + 1; g <= NSEG; ++g) seg_start[g] = N;
        }
    }
}

// ---------------- Kernel 2: single-pass fused gate+softmax+readout ----------------
// One 256-thread block per segment. Online softmax (flash-style): each feat
// row is read from HBM exactly ONCE, used for the gate dot AND the weighted
// accumulation while in registers. 16 rows per tile, 1 barrier per tile,
// next tile prefetched before the barrier.
// Thread layout: rg = tid>>5 (row group 0..7), c = tid&31 (float4 column).
// Row group rg owns rows base+rg and base+rg+8 of each 16-row tile.
__global__ __launch_bounds__(256) void fused_kernel(
        const float* __restrict__ feat,
        const float* __restrict__ gw,
        const float* __restrict__ gb,
        const int*  __restrict__ seg_start,
        float* __restrict__ out) {
    __shared__ float  gs[2][16];      // double-buffered per-tile gates
    __shared__ float4 red[8][32];

    int g   = blockIdx.x;
    int s   = seg_start[g];
    int e   = seg_start[g + 1];
    int len = e - s;

    int tid = threadIdx.x;
    int rg  = tid >> 5;
    int c   = tid & 31;

    const float4* f4 = (const float4*)feat;
    float4 w4 = ((const float4*)gw)[c];
    float  b0 = gb[0];

    float  m   = -INFINITY;
    float  l   = 0.0f;
    float4 acc = {0.f, 0.f, 0.f, 0.f};

    int nt = (len + 15) >> 4;

    // prefetch tile 0
    float4 va = {0.f,0.f,0.f,0.f}, vb = {0.f,0.f,0.f,0.f};
    {
        int n1 = s + rg, n2 = n1 + 8;
        if (n1 < e) va = f4[n1 * 32 + c];
        if (n2 < e) vb = f4[n2 * 32 + c];
    }

    for (int t = 0; t < nt; ++t) {
        int base = s + t * 16;
        int n1 = base + rg, n2 = n1 + 8;
        float4 ca = va, cb = vb;

        // prefetch next tile (issued before this tile's barrier -> latency hidden)
        int p1 = n1 + 16, p2 = n2 + 16;
        va = make_float4(0.f,0.f,0.f,0.f);
        vb = make_float4(0.f,0.f,0.f,0.f);
        if (p1 < e) va = f4[p1 * 32 + c];
        if (p2 < e) vb = f4[p2 * 32 + c];

        // gate dots for this thread's two rows; reduce across the 32-lane half
        float d1 = ca.x*w4.x + ca.y*w4.y + ca.z*w4.z + ca.w*w4.w;
        float d2 = cb.x*w4.x + cb.y*w4.y + cb.z*w4.z + cb.w*w4.w;
        #pragma unroll
        for (int off = 16; off; off >>= 1) {
            d1 += __shfl_xor(d1, off);
            d2 += __shfl_xor(d2, off);
        }
        if (c == 0) {
            gs[t & 1][rg]     = (n1 < e) ? d1 + b0 : -INFINITY;
            gs[t & 1][rg + 8] = (n2 < e) ? d2 + b0 : -INFINITY;
        }
        __syncthreads();

        // per-16-lane-group parallel max & expsum over the 16 tile gates
        float gj = gs[t & 1][tid & 15];           // lanes 0..15 cover j=0..15
        float tmax = gj;
        #pragma unroll
        for (int off = 8; off; off >>= 1) tmax = fmaxf(tmax, __shfl_xor(tmax, off));
        float m_new = fmaxf(m, tmax);             // finite: tile has >=1 valid row
        float scale = __expf(m - m_new);          // first tile: exp(-inf)=0, acc/l are 0
        float pj = __expf(gj - m_new);            // OOB rows: exp(-inf)=0
        float psum = pj;
        #pragma unroll
        for (int off = 8; off; off >>= 1) psum += __shfl_xor(psum, off);
        l = l * scale + psum;

        float pa = __expf(gs[t & 1][rg]     - m_new);
        float pb = __expf(gs[t & 1][rg + 8] - m_new);
        acc.x = acc.x * scale + pa * ca.x + pb * cb.x;
        acc.y = acc.y * scale + pa * ca.y + pb * cb.y;
        acc.z = acc.z * scale + pa * ca.z + pb * cb.z;
        acc.w = acc.w * scale + pa * ca.w + pb * cb.w;
        m = m_new;
        // note: gs buffer t&1 is re-written only at t+2, after barrier t+1 -> safe
    }

    // reduce the 8 row-group partial accumulators, normalize, write
    red[rg][c] = acc;
    __syncthreads();
    if (rg == 0) {
        float4 r = red[0][c];
        #pragma unroll
        for (int k = 1; k < 8; ++k) {
            float4 v = red[k][c];
            r.x += v.x; r.y += v.y; r.z += v.z; r.w += v.w;
        }
        float invl = (len > 0) ? 1.0f / l : 0.0f;   // empty segment -> zeros
        r.x *= invl; r.y *= invl; r.z *= invl; r.w *= invl;
        ((float4*)out)[g * 32 + c] = r;
    }
}

// ---------------- launch ----------------
extern "C" void kernel_launch(void* const* d_in, const int* in_sizes, int n_in,
                              void* d_out, int out_size, void* d_ws, size_t ws_size,
                              hipStream_t stream) {
    const float* feat = (const float*)d_in[0];
    const float* gw   = (const float*)d_in[1];
    const float* gb   = (const float*)d_in[2];
    const int*   seg  = (const int*)d_in[3];
    int N = in_sizes[0] / DD;                        // 500000

    int* seg_start = (int*)d_ws;                     // NSEG+1 ints

    bounds_kernel<<<1024, 256, 0, stream>>>(seg, seg_start, N);
    fused_kernel<<<NSEG, 256, 0, stream>>>(feat, gw, gb, seg_start, (float*)d_out);
}

// Round 4
// 50.688 us; speedup vs baseline: 1.8014x; 1.0504x over previous
//
#include <hip/hip_runtime.h>
#include <math.h>

#define NSEG 4096
#define DD   128

typedef float f4 __attribute__((ext_vector_type(4)));

// first index n with seg[n] >= g (seg sorted ascending)
__device__ __forceinline__ int lower_bound(const int* __restrict__ seg, int N, int g) {
    int lo = 0, hi = N;
    while (lo < hi) {
        int mid = (lo + hi) >> 1;
        if (seg[mid] < g) lo = mid + 1; else hi = mid;
    }
    return lo;
}

// ---------------- single fused kernel: bounds + gate + online softmax + readout ----------------
// One 256-thread block per segment. 32-row tiles, 4 rows per thread
// (rows base+rg, +8, +16, +24), one barrier per tile, next tile prefetched
// before the barrier. feat read exactly once (non-temporal).
__global__ __launch_bounds__(256) void fused_kernel(
        const float* __restrict__ feat,
        const float* __restrict__ gw,
        const float* __restrict__ gb,
        const int*  __restrict__ seg,
        int N,
        float* __restrict__ out) {
    __shared__ float gs[2][32];     // double-buffered per-tile gates
    __shared__ f4    red[8][32];

    int g = blockIdx.x;
    int s = lower_bound(seg, N, g);         // uniform across block -> scalar loads
    int e = lower_bound(seg, N, g + 1);
    int len = e - s;

    int tid = threadIdx.x;
    int rg  = tid >> 5;     // row group 0..7
    int c   = tid & 31;     // float4 column

    const f4* fp = (const f4*)feat;
    f4    w4 = ((const f4*)gw)[c];
    float b0 = gb[0];

    float m = -INFINITY, l = 0.0f;
    f4 acc = {0.f, 0.f, 0.f, 0.f};

    int ntiles = (len + 31) >> 5;

    // prefetch tile 0
    f4 va = {0,0,0,0}, vb = {0,0,0,0}, vc = {0,0,0,0}, vd = {0,0,0,0};
    {
        int n1 = s + rg;
        if (n1      < e) va = __builtin_nontemporal_load(&fp[(n1     ) * 32 + c]);
        if (n1 + 8  < e) vb = __builtin_nontemporal_load(&fp[(n1 + 8 ) * 32 + c]);
        if (n1 + 16 < e) vc = __builtin_nontemporal_load(&fp[(n1 + 16) * 32 + c]);
        if (n1 + 24 < e) vd = __builtin_nontemporal_load(&fp[(n1 + 24) * 32 + c]);
    }

    for (int t = 0; t < ntiles; ++t) {
        int base = s + t * 32;
        int n1 = base + rg;
        f4 ca = va, cb = vb, cc = vc, cd = vd;

        // prefetch next tile (issued before this tile's barrier)
        int p1 = n1 + 32;
        va = (f4){0,0,0,0}; vb = (f4){0,0,0,0}; vc = (f4){0,0,0,0}; vd = (f4){0,0,0,0};
        if (p1      < e) va = __builtin_nontemporal_load(&fp[(p1     ) * 32 + c]);
        if (p1 + 8  < e) vb = __builtin_nontemporal_load(&fp[(p1 + 8 ) * 32 + c]);
        if (p1 + 16 < e) vc = __builtin_nontemporal_load(&fp[(p1 + 16) * 32 + c]);
        if (p1 + 24 < e) vd = __builtin_nontemporal_load(&fp[(p1 + 24) * 32 + c]);

        // gate dots for this thread's 4 rows; reduce across the 32-lane half
        float d1 = ca.x*w4.x + ca.y*w4.y + ca.z*w4.z + ca.w*w4.w;
        float d2 = cb.x*w4.x + cb.y*w4.y + cb.z*w4.z + cb.w*w4.w;
        float d3 = cc.x*w4.x + cc.y*w4.y + cc.z*w4.z + cc.w*w4.w;
        float d4 = cd.x*w4.x + cd.y*w4.y + cd.z*w4.z + cd.w*w4.w;
        #pragma unroll
        for (int off = 16; off; off >>= 1) {
            d1 += __shfl_xor(d1, off);
            d2 += __shfl_xor(d2, off);
            d3 += __shfl_xor(d3, off);
            d4 += __shfl_xor(d4, off);
        }
        int buf = t & 1;
        if (c == 0) {
            gs[buf][rg]      = (n1      < e) ? d1 + b0 : -INFINITY;
            gs[buf][rg + 8]  = (n1 + 8  < e) ? d2 + b0 : -INFINITY;
            gs[buf][rg + 16] = (n1 + 16 < e) ? d3 + b0 : -INFINITY;
            gs[buf][rg + 24] = (n1 + 24 < e) ? d4 + b0 : -INFINITY;
        }
        __syncthreads();
        // (gs[buf] is next rewritten at t+2, which is after barrier t+1 -> safe)

        // 32-lane-parallel max & expsum over the 32 tile gates
        float gj = gs[buf][tid & 31];
        float tmax = gj;
        #pragma unroll
        for (int off = 16; off; off >>= 1) tmax = fmaxf(tmax, __shfl_xor(tmax, off));
        float m_new = fmaxf(m, tmax);           // finite: tile has >=1 valid row
        float scale = __expf(m - m_new);        // first tile: exp(-inf)=0; acc,l are 0
        float pj = __expf(gj - m_new);          // OOB rows: exp(-inf)=0
        float psum = pj;
        #pragma unroll
        for (int off = 16; off; off >>= 1) psum += __shfl_xor(psum, off);
        l = l * scale + psum;

        float pa = __expf(gs[buf][rg]      - m_new);
        float pb = __expf(gs[buf][rg + 8]  - m_new);
        float pc = __expf(gs[buf][rg + 16] - m_new);
        float pd = __expf(gs[buf][rg + 24] - m_new);
        acc = acc * scale + pa * ca + pb * cb + pc * cc + pd * cd;
        m = m_new;
    }

    // reduce the 8 row-group partial accumulators, normalize, write
    red[rg][c] = acc;
    __syncthreads();
    if (rg == 0) {
        f4 r = red[0][c];
        #pragma unroll
        for (int k = 1; k < 8; ++k) r += red[k][c];
        float invl = (len > 0) ? 1.0f / l : 0.0f;   // empty segment -> zeros
        r *= invl;
        ((f4*)out)[g * 32 + c] = r;
    }
}

// ---------------- launch ----------------
extern "C" void kernel_launch(void* const* d_in, const int* in_sizes, int n_in,
                              void* d_out, int out_size, void* d_ws, size_t ws_size,
                              hipStream_t stream) {
    const float* feat = (const float*)d_in[0];
    const float* gw   = (const float*)d_in[1];
    const float* gb   = (const float*)d_in[2];
    const int*   seg  = (const int*)d_in[3];
    int N = in_sizes[0] / DD;                        // 500000

    fused_kernel<<<NSEG, 256, 0, stream>>>(feat, gw, gb, seg, N, (float*)d_out);
}